// Round 4
// baseline (52.231 us; speedup 1.0000x reference)
//
#include <hip/hip_runtime.h>

#define VBUCKETS 2048          // 11-bit order-preserving float key
#define NCOPIES 2              // LDS histogram copies (by half-block)
#define HSIZE (NCOPIES * 2 * VBUCKETS)   // copies x classes x vbuckets
#define H_THREADS 512
#define FIN_THREADS 1024
#define BPT (VBUCKETS / FIN_THREADS)     // = 2

// ws layout: g_cnt u32[2*VBUCKETS] | g_sum u64[2*VBUCKETS] | g_maxkey u32
#define CNT_BYTES (2 * VBUCKETS * 4)
#define SUM_BYTES (2 * VBUCKETS * 8)

// ---------------------------------------------------------------------------
// K1: privatized LDS histogram, ONE packed ds_add_u64 per element.
//   entry = (count << 44) | fixedpoint_sum(|e| * 2^24)
//   region = copy*2 + class; physical vkey rotated by region*5 so the hot
//   buckets of the 4 regions land on different LDS banks ({0,10,20,30}).
//   idx = (copy<<12) | (class<<11) | ((vkey + region*5) & 2047)
// ---------------------------------------------------------------------------
__global__ __launch_bounds__(H_THREADS) void lovasz_hist(
    const float* __restrict__ logits, const int* __restrict__ targets,
    unsigned int* __restrict__ g_cnt, unsigned long long* __restrict__ g_sum,
    unsigned int* __restrict__ g_maxkey, int n)
{
    __shared__ unsigned long long h[HSIZE];   // 64 KB
    __shared__ unsigned int smax;

    const int tid = threadIdx.x;
    for (int i = tid; i < HSIZE; i += blockDim.x) h[i] = 0ULL;
    if (tid == 0) smax = 0u;
    __syncthreads();

    const unsigned copy = (tid >> 8) & (NCOPIES - 1);   // half-block -> copy
    const unsigned copyBase = copy << 12;
    const unsigned rotBase = copy * 2;                  // region = rotBase+cls
    unsigned int lmax = 0u;
    const long long gthreads = (long long)gridDim.x * blockDim.x;
    const long long gid = (long long)blockIdx.x * blockDim.x + tid;
    const long long stride = gthreads * 4;

#define PROC(lv, tv) {                                                        \
        float e = (tv) ? (1.0f - (lv)) : (1.0f + (lv));                       \
        unsigned u = __float_as_uint(e);                                      \
        unsigned key = (u & 0x80000000u) ? ~u : (u | 0x80000000u);            \
        unsigned cls = (unsigned)((tv) != 0);                                 \
        unsigned pv = ((key >> 21) + (rotBase + cls) * 5) & (VBUCKETS - 1);   \
        unsigned idx = copyBase | (cls << 11) | pv;                           \
        unsigned sfix = (unsigned)(fabsf(e) * 16777216.0f);                   \
        atomicAdd(&h[idx], (1ULL << 44) | (unsigned long long)sfix);          \
        if (key > lmax) lmax = key; }

    for (long long i = gid * 4; i + 3 < (long long)n; i += stride) {
        const float4 L = *reinterpret_cast<const float4*>(logits + i);
        const int4  T = *reinterpret_cast<const int4*>(targets + i);
        PROC(L.x, T.x) PROC(L.y, T.y) PROC(L.z, T.z) PROC(L.w, T.w)
    }
    for (long long j = (long long)(n & ~3) + gid; j < (long long)n; j += gthreads) {
        float lv = logits[j]; int tv = targets[j];
        PROC(lv, tv)
    }
#undef PROC

    // wave-reduce max key, one LDS atomic per wave
    for (int off = 32; off > 0; off >>= 1) {
        unsigned o = (unsigned)__shfl_xor((int)lmax, off);
        if (o > lmax) lmax = o;
    }
    if ((tid & 63) == 0) atomicMax(&smax, lmax);
    __syncthreads();

    // flush logical entries: merge the two copies (un-rotating each region)
    for (int j = tid; j < 2 * VBUCKETS; j += blockDim.x) {
        const unsigned cls  = (unsigned)j >> 11;
        const unsigned vkey = (unsigned)j & (VBUCKETS - 1);
        const unsigned p0 = (cls << 11) | ((vkey + cls * 5) & (VBUCKETS - 1));
        const unsigned p1 = (1u << 12) | (cls << 11)
                          | ((vkey + (2 + cls) * 5) & (VBUCKETS - 1));
        unsigned long long hv = h[p0] + h[p1];
        if (hv) {
            atomicAdd(&g_cnt[j], (unsigned)(hv >> 44));
            atomicAdd(&g_sum[j], hv & ((1ULL << 44) - 1ULL));
        }
    }
    if (tid == 0) atomicMax(g_maxkey, smax);
}

// ---------------------------------------------------------------------------
// K2: single block. Suffix scan over buckets (descending value order),
// midpoint-ratio dot over ALL buckets, grad[0] correction, scalar out.
//   c_b = cnt[0][b]+cnt[1][b], p_b = cnt[1][b]
//   S_b = sign(b) * (sum[0][b]+sum[1][b]) * 2^-24
//   tau_b = (I - Fp - p_b/2) / (n - F - c_b/2)
//   out = sum_b S_b*tau_b - e_max * I / n
// ---------------------------------------------------------------------------
__global__ __launch_bounds__(FIN_THREADS) void lovasz_final(
    const unsigned int* __restrict__ g_cnt, const unsigned long long* __restrict__ g_sum,
    const unsigned int* __restrict__ g_maxkey, float* __restrict__ out, int n)
{
    const int t = threadIdx.x;
    __shared__ unsigned int sc[FIN_THREADS], sp[FIN_THREADS];
    __shared__ double sd[FIN_THREADS];

    unsigned c[BPT], p[BPT];
    double sv[BPT];
    unsigned ct = 0, pt = 0;
    for (int k = 0; k < BPT; ++k) {
        const int b = t * BPT + k;
        unsigned c1 = g_cnt[VBUCKETS + b];
        c[k] = g_cnt[b] + c1;
        p[k] = c1;
        double mag = (double)(g_sum[b] + g_sum[VBUCKETS + b]) * (1.0 / 16777216.0);
        sv[k] = (b >= VBUCKETS / 2) ? mag : -mag;
        ct += c[k]; pt += p[k];
    }
    sc[t] = ct; sp[t] = pt;
    __syncthreads();

    // inclusive suffix scan over thread partials (Hillis-Steele)
    for (int off = 1; off < FIN_THREADS; off <<= 1) {
        unsigned a = (t + off < FIN_THREADS) ? sc[t + off] : 0u;
        unsigned b = (t + off < FIN_THREADS) ? sp[t + off] : 0u;
        __syncthreads();
        sc[t] += a; sp[t] += b;
        __syncthreads();
    }

    const unsigned I = sp[0];
    const double dn = (double)n;
    const double dI = (double)I;

    unsigned F  = sc[t] - ct;     // elements in strictly-higher threads' buckets
    unsigned Fp = sp[t] - pt;
    double acc = 0.0;
    for (int k = BPT - 1; k >= 0; --k) {
        if (c[k]) {
            const double tau = (dI - (double)Fp - 0.5 * (double)p[k])
                             / (dn - (double)F - 0.5 * (double)c[k]);
            acc += sv[k] * tau;
        }
        F += c[k]; Fp += p[k];
    }

    sd[t] = acc;
    __syncthreads();
    for (int off = FIN_THREADS / 2; off > 0; off >>= 1) {
        if (t < off) sd[t] += sd[t + off];
        __syncthreads();
    }

    if (t == 0) {
        unsigned mk = *g_maxkey;
        unsigned mu = (mk & 0x80000000u) ? (mk & 0x7FFFFFFFu) : ~mk;
        float emax = __uint_as_float(mu);
        out[0] = (float)(sd[0] - (double)emax * dI / dn);
    }
}

extern "C" void kernel_launch(void* const* d_in, const int* in_sizes, int n_in,
                              void* d_out, int out_size, void* d_ws, size_t ws_size,
                              hipStream_t stream)
{
    const float* logits  = (const float*)d_in[0];
    const int*   targets = (const int*)d_in[1];
    const int n = in_sizes[0];

    unsigned int* g_cnt = (unsigned int*)d_ws;
    unsigned long long* g_sum = (unsigned long long*)((char*)d_ws + CNT_BYTES);
    unsigned int* g_maxkey = (unsigned int*)((char*)d_ws + CNT_BYTES + SUM_BYTES);

    hipMemsetAsync(d_ws, 0, CNT_BYTES + SUM_BYTES + 256, stream);

    hipLaunchKernelGGL(lovasz_hist, dim3(1024), dim3(H_THREADS), 0, stream,
                       logits, targets, g_cnt, g_sum, g_maxkey, n);
    hipLaunchKernelGGL(lovasz_final, dim3(1), dim3(FIN_THREADS), 0, stream,
                       g_cnt, g_sum, g_maxkey, (float*)d_out, n);
}

// Round 5
// 49.851 us; speedup vs baseline: 1.0477x; 1.0477x over previous
//
#include <hip/hip_runtime.h>

#define KEYBITS 13
#define VBUCKETS (1 << KEYBITS)          // 8192 value buckets
#define HSIZE (2 * VBUCKETS)             // class-interleaved: idx = vk*2 + cls
#define H_THREADS 1024
#define H_BLOCKS 512                     // 2 blocks/CU on 256 CUs
#define FIN_THREADS 1024
#define BPT (VBUCKETS / FIN_THREADS)     // = 8

// ws layout: g_cnt u32[HSIZE] | g_maxkey u32
#define CNT_BYTES (HSIZE * 4)

// ---------------------------------------------------------------------------
// K1: counts-only privatized LDS histogram. ONE ds_add_u32 per element.
//   key  = 13-bit order-preserving float key (larger e -> larger key)
//   idx  = (key>>19)*2 + class   -> hot buckets cover all 32 LDS banks
//   S_b is reconstructed in K2 as count * bucket-midpoint (exact to first
//   order: key<->value is linear within a bucket since exponent is fixed).
// ---------------------------------------------------------------------------
__global__ __launch_bounds__(H_THREADS) void lovasz_hist(
    const float* __restrict__ logits, const int* __restrict__ targets,
    unsigned int* __restrict__ g_cnt, unsigned int* __restrict__ g_maxkey, int n)
{
    __shared__ unsigned int h[HSIZE];    // 64 KB
    __shared__ unsigned int smax;

    const int tid = threadIdx.x;
    for (int i = tid; i < HSIZE; i += blockDim.x) h[i] = 0u;
    if (tid == 0) smax = 0u;
    __syncthreads();

    unsigned int lmax = 0u;
    const long long gthreads = (long long)gridDim.x * blockDim.x;
    const long long gid = (long long)blockIdx.x * blockDim.x + tid;
    const long long stride = gthreads * 4;

#define PROC(lv, tv) {                                                        \
        float e = (tv) ? (1.0f - (lv)) : (1.0f + (lv));                       \
        unsigned u = __float_as_uint(e);                                      \
        unsigned key = (u & 0x80000000u) ? ~u : (u | 0x80000000u);            \
        unsigned idx = ((key >> (32 - KEYBITS)) << 1) | (unsigned)((tv) != 0);\
        atomicAdd(&h[idx], 1u);                                               \
        if (key > lmax) lmax = key; }

    for (long long i = gid * 4; i + 3 < (long long)n; i += stride) {
        const float4 L = *reinterpret_cast<const float4*>(logits + i);
        const int4  T = *reinterpret_cast<const int4*>(targets + i);
        PROC(L.x, T.x) PROC(L.y, T.y) PROC(L.z, T.z) PROC(L.w, T.w)
    }
    for (long long j = (long long)(n & ~3) + gid; j < (long long)n; j += gthreads) {
        float lv = logits[j]; int tv = targets[j];
        PROC(lv, tv)
    }
#undef PROC

    // wave-reduce max key, one LDS atomic per wave
    for (int off = 32; off > 0; off >>= 1) {
        unsigned o = (unsigned)__shfl_xor((int)lmax, off);
        if (o > lmax) lmax = o;
    }
    if ((tid & 63) == 0) atomicMax(&smax, lmax);
    __syncthreads();

    // flush non-empty entries (few hundred of 16384)
    for (int i = tid; i < HSIZE; i += blockDim.x) {
        unsigned hv = h[i];
        if (hv) atomicAdd(&g_cnt[i], hv);
    }
    if (tid == 0) atomicMax(g_maxkey, smax);
}

// ---------------------------------------------------------------------------
// K2: single block. Suffix scan over buckets (descending value order),
// midpoint-ratio dot over ALL buckets, grad[0] correction, scalar out.
//   c_b = cnt[2b] + cnt[2b+1], p_b = cnt[2b+1]
//   S_b = c_b * val(key_mid(b))        (bucket midpoint value, signed)
//   tau_b = (I - Fp - p_b/2) / (n - F - c_b/2)
//   out = sum_b S_b*tau_b - e_max * I / n
// ---------------------------------------------------------------------------
__global__ __launch_bounds__(FIN_THREADS) void lovasz_final(
    const unsigned int* __restrict__ g_cnt, const unsigned int* __restrict__ g_maxkey,
    float* __restrict__ out, int n)
{
    const int t = threadIdx.x;
    __shared__ unsigned int sc[FIN_THREADS], sp[FIN_THREADS];
    __shared__ double sd[FIN_THREADS];

    unsigned c[BPT], p[BPT];
    double sv[BPT];
    unsigned ct = 0, pt = 0;
    for (int k = 0; k < BPT; ++k) {
        const int b = t * BPT + k;
        unsigned c1 = g_cnt[2 * b + 1];
        c[k] = g_cnt[2 * b] + c1;
        p[k] = c1;
        // bucket midpoint value (key -> float inverse map)
        unsigned kmid = ((unsigned)b << (32 - KEYBITS)) | (1u << (31 - KEYBITS));
        unsigned u = (kmid & 0x80000000u) ? (kmid & 0x7FFFFFFFu) : ~kmid;
        sv[k] = (double)c[k] * (double)__uint_as_float(u);
        ct += c[k]; pt += p[k];
    }
    sc[t] = ct; sp[t] = pt;
    __syncthreads();

    // inclusive suffix scan over thread partials (Hillis-Steele)
    for (int off = 1; off < FIN_THREADS; off <<= 1) {
        unsigned a = (t + off < FIN_THREADS) ? sc[t + off] : 0u;
        unsigned b = (t + off < FIN_THREADS) ? sp[t + off] : 0u;
        __syncthreads();
        sc[t] += a; sp[t] += b;
        __syncthreads();
    }

    const unsigned I = sp[0];
    const double dn = (double)n;
    const double dI = (double)I;

    unsigned F  = sc[t] - ct;     // elements in strictly-higher threads' buckets
    unsigned Fp = sp[t] - pt;
    double acc = 0.0;
    for (int k = BPT - 1; k >= 0; --k) {
        if (c[k]) {
            const double tau = (dI - (double)Fp - 0.5 * (double)p[k])
                             / (dn - (double)F - 0.5 * (double)c[k]);
            acc += sv[k] * tau;
        }
        F += c[k]; Fp += p[k];
    }

    sd[t] = acc;
    __syncthreads();
    for (int off = FIN_THREADS / 2; off > 0; off >>= 1) {
        if (t < off) sd[t] += sd[t + off];
        __syncthreads();
    }

    if (t == 0) {
        unsigned mk = *g_maxkey;
        unsigned mu = (mk & 0x80000000u) ? (mk & 0x7FFFFFFFu) : ~mk;
        float emax = __uint_as_float(mu);
        out[0] = (float)(sd[0] - (double)emax * dI / dn);
    }
}

extern "C" void kernel_launch(void* const* d_in, const int* in_sizes, int n_in,
                              void* d_out, int out_size, void* d_ws, size_t ws_size,
                              hipStream_t stream)
{
    const float* logits  = (const float*)d_in[0];
    const int*   targets = (const int*)d_in[1];
    const int n = in_sizes[0];

    unsigned int* g_cnt = (unsigned int*)d_ws;
    unsigned int* g_maxkey = (unsigned int*)((char*)d_ws + CNT_BYTES);

    hipMemsetAsync(d_ws, 0, CNT_BYTES + 256, stream);

    hipLaunchKernelGGL(lovasz_hist, dim3(H_BLOCKS), dim3(H_THREADS), 0, stream,
                       logits, targets, g_cnt, g_maxkey, n);
    hipLaunchKernelGGL(lovasz_final, dim3(1), dim3(FIN_THREADS), 0, stream,
                       g_cnt, g_maxkey, (float*)d_out, n);
}